// Round 7
// baseline (444.024 us; speedup 1.0000x reference)
//
#include <hip/hip_runtime.h>
#include <stdint.h>

#define Ll 2048
#define Mrows 4096
#define LOG2E 1.44269504088896f

typedef unsigned short u16;
typedef __attribute__((ext_vector_type(8))) short short8;
typedef __attribute__((ext_vector_type(4))) float f32x4;

#if __has_builtin(__builtin_amdgcn_exp2f)
#define EXP2F(x) __builtin_amdgcn_exp2f(x)
#else
#define EXP2F(x) exp2f(x)
#endif

__device__ __forceinline__ float b2f(u16 b) {
  union { float f; unsigned u; } x; x.u = ((unsigned)b) << 16; return x.f;
}
__device__ __forceinline__ u16 f2b(float v) {
  union { float f; unsigned u; } x; x.f = v;
  unsigned r = x.u + 0x7fffu + ((x.u >> 16) & 1u);
  return (u16)(r >> 16);
}

#define GLOAD_LDS16(gp, sp)                                                        \
  __builtin_amdgcn_global_load_lds(                                                \
      (__attribute__((address_space(1))) void*)(void*)(gp),                        \
      (__attribute__((address_space(3))) void*)(sp), 16, 0, 0)

// ---------------- merged convert: 4 weights fp32->bf16, attn_bias -> bf16*log2e ----
__global__ __launch_bounds__(256) void k_convert_all(
    const float* __restrict__ s0, u16* __restrict__ d0,
    const float* __restrict__ s1, u16* __restrict__ d1,
    const float* __restrict__ s2, u16* __restrict__ d2,
    const float* __restrict__ s3, u16* __restrict__ d3,
    const float* __restrict__ s4, u16* __restrict__ d4) {
  int i = blockIdx.x * 256 + threadIdx.x;  // 0..4194303, exact
  if (i >= 3145728) {  // attn_bias * log2e -> bf16
    i -= 3145728;
    const float4 v = ((const float4*)s4)[i];
    ushort4 o;
    o.x = f2b(v.x * LOG2E); o.y = f2b(v.y * LOG2E);
    o.z = f2b(v.z * LOG2E); o.w = f2b(v.w * LOG2E);
    ((ushort4*)d4)[i] = o;
    return;
  }
  const float* s; u16* d; int off;
  if (i < 786432)       { s = s0; d = d0; off = 0; }
  else if (i < 1048576) { s = s1; d = d1; off = 786432; }
  else if (i < 2097152) { s = s2; d = d2; off = 1048576; }
  else                  { s = s3; d = d3; off = 2097152; }
  i -= off;
  const float4 v = ((const float4*)s)[i];
  ushort4 o;
  o.x = f2b(v.x); o.y = f2b(v.y); o.z = f2b(v.z); o.w = f2b(v.w);
  ((ushort4*)d)[i] = o;
}

// ---------------- ada = silu(cond) @ ada_w.T + ada_b ----------------
__global__ __launch_bounds__(256) void k_ada(const float* __restrict__ cond,
                                             const float* __restrict__ aw,
                                             const float* __restrict__ ab,
                                             float* __restrict__ out) {
  const int wv = threadIdx.x >> 6, lane = threadIdx.x & 63;
  const int j = blockIdx.x * 4 + wv;  // 0..12287
  const int b = j / 6144, jj = j % 6144;
  const float* wr = aw + (size_t)jj * 1024;
  const float* cr = cond + b * 1024;
  float acc = 0.f;
  for (int d = lane; d < 1024; d += 64) {
    const float cv = cr[d];
    acc += (cv / (1.f + __expf(-cv))) * wr[d];
  }
  for (int off = 32; off; off >>= 1) acc += __shfl_xor(acc, off);
  if (lane == 0) out[b * 6144 + jj] = acc + ab[jj];
}

// ---------------- LN(x)*(1+s)+sh -> bf16 ----------------
__global__ __launch_bounds__(256) void k_ln_mod(const float* __restrict__ x,
                                                const float* __restrict__ ada,
                                                u16* __restrict__ out,
                                                int s_off, int sh_off) {
  const int row = blockIdx.x;
  const int b = row >> 11;
  const int t = threadIdx.x;
  const float4 xv = ((const float4*)(x + (size_t)row * 1024))[t];
  float s = xv.x + xv.y + xv.z + xv.w;
  float s2 = xv.x * xv.x + xv.y * xv.y + xv.z * xv.z + xv.w * xv.w;
  for (int off = 32; off; off >>= 1) { s += __shfl_xor(s, off); s2 += __shfl_xor(s2, off); }
  __shared__ float red[8];
  const int wv = t >> 6, lane = t & 63;
  if (lane == 0) { red[wv] = s; red[4 + wv] = s2; }
  __syncthreads();
  s = red[0] + red[1] + red[2] + red[3];
  s2 = red[4] + red[5] + red[6] + red[7];
  const float mean = s * (1.f / 1024.f);
  const float var = s2 * (1.f / 1024.f) - mean * mean;
  const float rstd = rsqrtf(var + 1e-6f);
  const float4 sv = ((const float4*)(ada + b * 6144 + s_off))[t];
  const float4 shv = ((const float4*)(ada + b * 6144 + sh_off))[t];
  ushort4 ov;
  ov.x = f2b((xv.x - mean) * rstd * (1.f + sv.x) + shv.x);
  ov.y = f2b((xv.y - mean) * rstd * (1.f + sv.y) + shv.y);
  ov.z = f2b((xv.z - mean) * rstd * (1.f + sv.z) + shv.z);
  ov.w = f2b((xv.w - mean) * rstd * (1.f + sv.w) + shv.w);
  ((ushort4*)(out + (size_t)row * 1024))[t] = ov;
}

// ---------------- x2 = x + (p0+p1)*g1 ; LN(x2)*(1+s2)+sh2 -> bf16 ----------------
__global__ __launch_bounds__(256) void k_resid_ln(const float* __restrict__ x,
                                                  const float* __restrict__ p0,
                                                  const float* __restrict__ p1,
                                                  const float* __restrict__ ada,
                                                  float* __restrict__ x2,
                                                  u16* __restrict__ out) {
  const int row = blockIdx.x;
  const int b = row >> 11;
  const int t = threadIdx.x;
  const float4 xv = ((const float4*)(x + (size_t)row * 1024))[t];
  const float4 pa = ((const float4*)(p0 + (size_t)row * 1024))[t];
  const float4 pb = ((const float4*)(p1 + (size_t)row * 1024))[t];
  const float4 gv = ((const float4*)(ada + b * 6144 + 0))[t];  // g1
  float4 v;
  v.x = xv.x + (pa.x + pb.x) * gv.x; v.y = xv.y + (pa.y + pb.y) * gv.y;
  v.z = xv.z + (pa.z + pb.z) * gv.z; v.w = xv.w + (pa.w + pb.w) * gv.w;
  ((float4*)(x2 + (size_t)row * 1024))[t] = v;
  float s = v.x + v.y + v.z + v.w;
  float s2 = v.x * v.x + v.y * v.y + v.z * v.z + v.w * v.w;
  for (int off = 32; off; off >>= 1) { s += __shfl_xor(s, off); s2 += __shfl_xor(s2, off); }
  __shared__ float red[8];
  const int wv = t >> 6, lane = t & 63;
  if (lane == 0) { red[wv] = s; red[4 + wv] = s2; }
  __syncthreads();
  s = red[0] + red[1] + red[2] + red[3];
  s2 = red[4] + red[5] + red[6] + red[7];
  const float mean = s * (1.f / 1024.f);
  const float var = s2 * (1.f / 1024.f) - mean * mean;
  const float rstd = rsqrtf(var + 1e-6f);
  const float4 sv = ((const float4*)(ada + b * 6144 + 3072))[t];   // s2 chunk
  const float4 shv = ((const float4*)(ada + b * 6144 + 5120))[t];  // sh2 chunk
  ushort4 ov;
  ov.x = f2b((v.x - mean) * rstd * (1.f + sv.x) + shv.x);
  ov.y = f2b((v.y - mean) * rstd * (1.f + sv.y) + shv.y);
  ov.z = f2b((v.z - mean) * rstd * (1.f + sv.z) + shv.z);
  ov.w = f2b((v.w - mean) * rstd * (1.f + sv.w) + shv.w);
  ((ushort4*)(out + (size_t)row * 1024))[t] = ov;
}

// ---------------- out = x2 + (f0+f1)*g2 ----------------
__global__ __launch_bounds__(256) void k_final(const float* __restrict__ x2,
                                               const float* __restrict__ f0,
                                               const float* __restrict__ f1,
                                               const float* __restrict__ ada,
                                               float* __restrict__ out) {
  const int i = blockIdx.x * 256 + threadIdx.x;
  const int elem = i * 4;
  const int b = elem >> 21;
  const int c = elem & 1023;
  const float4 xv = ((const float4*)x2)[i];
  const float4 fa = ((const float4*)f0)[i];
  const float4 fb = ((const float4*)f1)[i];
  const float4 gv = *(const float4*)(ada + b * 6144 + 1024 + c);
  float4 ov;
  ov.x = xv.x + (fa.x + fb.x) * gv.x; ov.y = xv.y + (fa.y + fb.y) * gv.y;
  ov.z = xv.z + (fa.z + fb.z) * gv.z; ov.w = xv.w + (fa.w + fb.w) * gv.w;
  ((float4*)out)[i] = ov;
}

// ---------------- bf16 MFMA GEMM: pipelined, XOR-swizzled LDS, opt split-K ----------
// LDS layout: row r's 16B chunk j stored at position j ^ (r&7)  (conflict-free b128
// reads: banks 4*(j^(r&7)) mod 32, 2-way). Staging lane reads global chunk
// (l&7)^(srow&7) so the wave-linear global_load_lds dest matches the swizzle.
// One barrier per K-tile, double-buffered As/Bs: prefetch of tile t+1 is issued
// right after the barrier opening tile t, so the next barrier's vmcnt drain waits
// on loads that had a full tile of compute in flight.
template <int OUT_BF16, int GELU_ACT>
__global__ __launch_bounds__(256, 2)
void k_gemm_bt(const u16* __restrict__ A, const u16* __restrict__ W,
               const float* __restrict__ bias, void* __restrict__ Cout,
               float* __restrict__ Cout2, int M, int N, int Kc) {
  __shared__ u16 As[2][128 * 64];
  __shared__ u16 Bs[2][128 * 64];
  const int tid = threadIdx.x;
  const int wv = tid >> 6;
  const int lane = tid & 63;
  const int q = lane >> 4;
  const int r = lane & 15;
  const int wm = (wv & 1) * 64;
  const int wn = (wv >> 1) * 64;
  const int m0 = blockIdx.x * 128;
  const int n0 = blockIdx.y * 128;
  const int K = Kc * gridDim.z;
  const int kt0 = blockIdx.z * Kc;

  f32x4 acc[4][4];
#pragma unroll
  for (int i = 0; i < 4; ++i)
#pragma unroll
    for (int j = 0; j < 4; ++j) acc[i][j] = (f32x4)0.0f;

  const int srow = tid >> 3;
  const int scol = ((tid & 7) ^ (srow & 7)) * 8;  // swizzled source chunk
  const u16* Ag = A + (size_t)(m0 + srow) * K + scol;
  const u16* Wg = W + (size_t)(n0 + srow) * K + scol;
  const int sw = r & 7;  // reader swizzle key

  auto stage = [&](int kt, int buf) __attribute__((always_inline)) {
#pragma unroll
    for (int p = 0; p < 4; ++p) {
      GLOAD_LDS16(Ag + (size_t)(p * 32) * K + kt, &As[buf][wv * 512 + p * 2048]);
      GLOAD_LDS16(Wg + (size_t)(p * 32) * K + kt, &Bs[buf][wv * 512 + p * 2048]);
    }
  };

  const int nt = Kc >> 6;
  stage(kt0, 0);
  for (int it = 0; it < nt; ++it) {
    const int cur = it & 1;
    __syncthreads();  // drains tile-it loads (issued one full tile ago)
    if (it + 1 < nt) stage(kt0 + (it + 1) * 64, cur ^ 1);
    const u16* AsC = As[cur];
    const u16* BsC = Bs[cur];
#pragma unroll
    for (int kc = 0; kc < 2; ++kc) {
      short8 af[4], bfr[4];
#pragma unroll
      for (int i = 0; i < 4; ++i) {
        af[i] = *(const short8*)(&AsC[(wm + i * 16 + r) * 64 + ((kc * 4 + q) ^ sw) * 8]);
        bfr[i] = *(const short8*)(&BsC[(wn + i * 16 + r) * 64 + ((kc * 4 + q) ^ sw) * 8]);
      }
#pragma unroll
      for (int mi = 0; mi < 4; ++mi)
#pragma unroll
        for (int ni = 0; ni < 4; ++ni)
          acc[mi][ni] = __builtin_amdgcn_mfma_f32_16x16x32_bf16(af[mi], bfr[ni],
                                                                acc[mi][ni], 0, 0, 0);
    }
  }
  float* Cf = (blockIdx.z == 0) ? (float*)Cout : Cout2;
#pragma unroll
  for (int mi = 0; mi < 4; ++mi) {
#pragma unroll
    for (int ni = 0; ni < 4; ++ni) {
      const int col = n0 + wn + ni * 16 + r;
      const float bv = (blockIdx.z == 0) ? bias[col] : 0.f;
#pragma unroll
      for (int rr = 0; rr < 4; ++rr) {
        const int rowg = m0 + wm + mi * 16 + q * 4 + rr;
        float v = acc[mi][ni][rr] + bv;
        if (GELU_ACT) {
          const float t = tanhf(0.7978845608028654f * (v + 0.044715f * v * v * v));
          v = 0.5f * v * (1.0f + t);
        }
        if (OUT_BF16)
          ((u16*)Cout)[(size_t)rowg * N + col] = f2b(v);
        else
          Cf[(size_t)rowg * N + col] = v;
      }
    }
  }
}

// ---------------- QKV GEMM (pipelined, swizzled) + fused bias + q/k L2-norm ------
__global__ __launch_bounds__(256, 2)
void k_gemm_qkv(const u16* __restrict__ A, const u16* __restrict__ W,
                const float* __restrict__ qb, const float* __restrict__ vb,
                const float* __restrict__ scale_mul, u16* __restrict__ Cout) {
  const int N = 3072, K = 1024;
  __shared__ u16 As[2][128 * 64];
  __shared__ u16 Bs[2][128 * 64];
  const int tid = threadIdx.x;
  const int wv = tid >> 6;
  const int lane = tid & 63;
  const int q = lane >> 4;
  const int r = lane & 15;
  const int wm = (wv & 1) * 64;
  const int wn = (wv >> 1) * 64;
  const int m0 = blockIdx.x * 128;
  const int n0 = blockIdx.y * 128;

  f32x4 acc[4][4];
#pragma unroll
  for (int i = 0; i < 4; ++i)
#pragma unroll
    for (int j = 0; j < 4; ++j) acc[i][j] = (f32x4)0.0f;

  const int srow = tid >> 3;
  const int scol = ((tid & 7) ^ (srow & 7)) * 8;
  const u16* Ag = A + (size_t)(m0 + srow) * K + scol;
  const u16* Wg = W + (size_t)(n0 + srow) * K + scol;
  const int sw = r & 7;

  auto stage = [&](int kt, int buf) __attribute__((always_inline)) {
#pragma unroll
    for (int p = 0; p < 4; ++p) {
      GLOAD_LDS16(Ag + (size_t)(p * 32) * K + kt, &As[buf][wv * 512 + p * 2048]);
      GLOAD_LDS16(Wg + (size_t)(p * 32) * K + kt, &Bs[buf][wv * 512 + p * 2048]);
    }
  };

  stage(0, 0);
  for (int it = 0; it < 16; ++it) {
    const int cur = it & 1;
    __syncthreads();
    if (it + 1 < 16) stage((it + 1) * 64, cur ^ 1);
    const u16* AsC = As[cur];
    const u16* BsC = Bs[cur];
#pragma unroll
    for (int kc = 0; kc < 2; ++kc) {
      short8 af[4], bfr[4];
#pragma unroll
      for (int i = 0; i < 4; ++i) {
        af[i] = *(const short8*)(&AsC[(wm + i * 16 + r) * 64 + ((kc * 4 + q) ^ sw) * 8]);
        bfr[i] = *(const short8*)(&BsC[(wn + i * 16 + r) * 64 + ((kc * 4 + q) ^ sw) * 8]);
      }
#pragma unroll
      for (int mi = 0; mi < 4; ++mi)
#pragma unroll
        for (int ni = 0; ni < 4; ++ni)
          acc[mi][ni] = __builtin_amdgcn_mfma_f32_16x16x32_bf16(af[mi], bfr[ni],
                                                                acc[mi][ni], 0, 0, 0);
    }
  }
  const int cb = n0 + wn;        // 64-aligned column base of this wave
  const int sec = cb >> 10;      // 0=q, 1=k, 2=v
  const int hh = (cb >> 6) & 15; // head index
  const float sm = (sec == 0)
      ? __expf(fminf(scale_mul[hh], 4.605170185988091f)) * LOG2E : 1.f;
#pragma unroll
  for (int mi = 0; mi < 4; ++mi) {
    float v[4][4];  // [ni][rr]
#pragma unroll
    for (int ni = 0; ni < 4; ++ni) {
      const int d = ni * 16 + r;
      const float bvv = (sec == 0) ? qb[(cb & 1023) + d]
                        : (sec == 2 ? vb[(cb & 1023) + d] : 0.f);
#pragma unroll
      for (int rr = 0; rr < 4; ++rr) v[ni][rr] = acc[mi][ni][rr] + bvv;
    }
    if (sec < 2) {
#pragma unroll
      for (int rr = 0; rr < 4; ++rr) {
        float ss = v[0][rr] * v[0][rr] + v[1][rr] * v[1][rr] +
                   v[2][rr] * v[2][rr] + v[3][rr] * v[3][rr];
        ss += __shfl_xor(ss, 1); ss += __shfl_xor(ss, 2);
        ss += __shfl_xor(ss, 4); ss += __shfl_xor(ss, 8);
        const float sc = rsqrtf(fmaxf(ss, 1e-24f)) * sm;
#pragma unroll
        for (int ni = 0; ni < 4; ++ni) v[ni][rr] *= sc;
      }
    }
#pragma unroll
    for (int ni = 0; ni < 4; ++ni) {
      const int col = cb + ni * 16 + r;
#pragma unroll
      for (int rr = 0; rr < 4; ++rr) {
        const int rowg = m0 + wm + mi * 16 + q * 4 + rr;
        Cout[(size_t)rowg * N + col] = f2b(v[ni][rr]);
      }
    }
  }
}

// ---------------- flash attention, MFMA bf16, pipelined + swizzled ----------------
// Qs/Ks XOR-swizzled (row r chunk j at position j^(r&7)) -> conflict-free b128 reads.
// Vt/Ps keep stride-72 rows (already 2-way). Bias is bf16*log2e, prefetched as raw
// u16 one tile ahead, converted at S-init (MFMA C-init carries it for free).
__global__ __launch_bounds__(512)
void k_flash(const u16* __restrict__ qkv, const u16* __restrict__ bias16,
             u16* __restrict__ o) {
  __shared__ u16 Qs[128 * 64];
  __shared__ u16 Ks[2][64 * 64];
  __shared__ u16 Vt[2][64 * 72];
  __shared__ u16 Ps[8][16 * 72];
  __shared__ float stat[8][16];
  const int tid = threadIdx.x;
  const int bh = blockIdx.x;
  const int qb = blockIdx.y;
  const int b = bh >> 4, h = bh & 15;
  const int wv = tid >> 6, lane = tid & 63;
  const int quad = lane >> 4, c = lane & 15;
  const u16* Qg = qkv + (size_t)b * Ll * 3072 + h * 64;
  const u16* Kg = Qg + 1024;
  const u16* Vg = Qg + 2048;
  const int srow = tid >> 3;
  const int scol = ((tid & 7) ^ (srow & 7)) * 8;  // swizzled source chunk
  const int vc = tid & 15, va = (tid >> 4) & 1, vd0 = (tid >> 5) * 4;
  const int swc = c & 7;

  {  // stage 128 Q rows (swizzled; rows r and r+64 share r&7)
    const u16* gp = Qg + (size_t)(qb * 128 + srow) * 3072 + scol;
    GLOAD_LDS16(gp, &Qs[wv * 512]);
    GLOAD_LDS16(gp + (size_t)64 * 3072, &Qs[4096 + wv * 512]);
  }

  f32x4 O[4];
  float lacc[4];
#pragma unroll
  for (int i = 0; i < 4; ++i) { O[i] = (f32x4)0.f; lacc[i] = 0.f; }
  const u16* bb = bias16 + (size_t)(qb * 128 + wv * 16 + quad * 4) * 2048 + c;

  // ---- prologue: stage tile 0
  u16 bA[4][4], bB[4][4];
  GLOAD_LDS16(Kg + (size_t)srow * 3072 + scol, &Ks[0][wv * 512]);
  {
    const u16* vp = Vg + (size_t)(va * 32 + vc) * 3072 + vd0;
    const ushort4 r0 = *(const ushort4*)vp;
    const ushort4 r1 = *(const ushort4*)(vp + (size_t)16 * 3072);
    u16* vt = &Vt[0][vd0 * 72 + vc * 4 + va * 2];
    *(unsigned*)(vt + 0 * 72) = (unsigned)r0.x | ((unsigned)r1.x << 16);
    *(unsigned*)(vt + 1 * 72) = (unsigned)r0.y | ((unsigned)r1.y << 16);
    *(unsigned*)(vt + 2 * 72) = (unsigned)r0.z | ((unsigned)r1.z << 16);
    *(unsigned*)(vt + 3 * 72) = (unsigned)r0.w | ((unsigned)r1.w << 16);
  }
#pragma unroll
  for (int ni = 0; ni < 4; ++ni)
#pragma unroll
    for (int rr = 0; rr < 4; ++rr) bA[ni][rr] = bb[rr * 2048 + ni * 16];

  auto tile = [&](int kt, u16* KsC, u16* KsN, u16* VtC, u16* VtN,
                  u16 (&bC)[4][4], u16 (&bN)[4][4]) __attribute__((always_inline)) {
    const int ktn = (kt < 31) ? kt + 1 : 31;
    __syncthreads();  // drains tile-kt loads (issued one full tile ago)
    // -- prefetch issue for tile kt+1
    GLOAD_LDS16(Kg + (size_t)(ktn * 64 + srow) * 3072 + scol, &KsN[wv * 512]);
    ushort4 vr0, vr1;
    {
      const u16* vp = Vg + (size_t)(ktn * 64 + va * 32 + vc) * 3072 + vd0;
      vr0 = *(const ushort4*)vp;
      vr1 = *(const ushort4*)(vp + (size_t)16 * 3072);
    }
#pragma unroll
    for (int ni = 0; ni < 4; ++ni)
#pragma unroll
      for (int rr = 0; rr < 4; ++rr)
        bN[ni][rr] = bb[rr * 2048 + ktn * 64 + ni * 16];
    // -- compute tile kt
    f32x4 S[4];
#pragma unroll
    for (int ni = 0; ni < 4; ++ni)
#pragma unroll
      for (int rr = 0; rr < 4; ++rr) S[ni][rr] = b2f(bC[ni][rr]);
#pragma unroll
    for (int ks = 0; ks < 2; ++ks) {
      const short8 aq =
          *(const short8*)(&Qs[(wv * 16 + c) * 64 + ((ks * 4 + quad) ^ swc) * 8]);
#pragma unroll
      for (int ni = 0; ni < 4; ++ni) {
        const short8 bk =
            *(const short8*)(&KsC[(ni * 16 + c) * 64 + ((ks * 4 + quad) ^ swc) * 8]);
        S[ni] = __builtin_amdgcn_mfma_f32_16x16x32_bf16(aq, bk, S[ni], 0, 0, 0);
      }
    }
#pragma unroll
    for (int rr = 0; rr < 4; ++rr) {
      union { float f; unsigned u; } p0, p1, p2, p3;
      p0.f = EXP2F(S[0][rr]); p1.f = EXP2F(S[1][rr]);
      p2.f = EXP2F(S[2][rr]); p3.f = EXP2F(S[3][rr]);
      lacc[rr] += (p0.f + p1.f) + (p2.f + p3.f);
      uint2 pk;
      pk.x = __builtin_amdgcn_perm(p1.u + 0x8000u, p0.u + 0x8000u, 0x07060302u);
      pk.y = __builtin_amdgcn_perm(p3.u + 0x8000u, p2.u + 0x8000u, 0x07060302u);
      *(uint2*)(&Ps[wv][(quad * 4 + rr) * 72 + c * 4]) = pk;
    }
    __threadfence_block();  // wave-local LDS visibility (Ps)
#pragma unroll
    for (int ks = 0; ks < 2; ++ks) {
      const short8 bp = *(const short8*)(&Ps[wv][c * 72 + ks * 32 + quad * 8]);
#pragma unroll
      for (int i = 0; i < 4; ++i) {
        const short8 av = *(const short8*)(&VtC[(i * 16 + c) * 72 + ks * 32 + quad * 8]);
        O[i] = __builtin_amdgcn_mfma_f32_16x16x32_bf16(av, bp, O[i], 0, 0, 0);
      }
    }
    // -- late write: V(kt+1) transpose into VtN
    {
      u16* vt = &VtN[vd0 * 72 + vc * 4 + va * 2];
      *(unsigned*)(vt + 0 * 72) = (unsigned)vr0.x | ((unsigned)vr1.x << 16);
      *(unsigned*)(vt + 1 * 72) = (unsigned)vr0.y | ((unsigned)vr1.y << 16);
      *(unsigned*)(vt + 2 * 72) = (unsigned)vr0.z | ((unsigned)vr1.z << 16);
      *(unsigned*)(vt + 3 * 72) = (unsigned)vr0.w | ((unsigned)vr1.w << 16);
    }
  };

  for (int kt = 0; kt < 32; kt += 2) {
    tile(kt,     Ks[0], Ks[1], Vt[0], Vt[1], bA, bB);
    tile(kt + 1, Ks[1], Ks[0], Vt[1], Vt[0], bB, bA);
  }

  // reduce l across the 16 col-lanes, broadcast per output row m=c
#pragma unroll
  for (int rr = 0; rr < 4; ++rr) {
    float l = lacc[rr];
    l += __shfl_xor(l, 1); l += __shfl_xor(l, 2);
    l += __shfl_xor(l, 4); l += __shfl_xor(l, 8);
    lacc[rr] = l;
  }
  if (c == 0)
    *(float4*)(&stat[wv][quad * 4]) = make_float4(lacc[0], lacc[1], lacc[2], lacc[3]);
  __threadfence_block();
  const float inv = 1.f / stat[wv][c];
  u16* op = o + (size_t)(b * Ll + qb * 128 + wv * 16 + c) * 1024 + h * 64;
#pragma unroll
  for (int i = 0; i < 4; ++i) {
    ushort4 ov;
    ov.x = f2b(O[i][0] * inv); ov.y = f2b(O[i][1] * inv);
    ov.z = f2b(O[i][2] * inv); ov.w = f2b(O[i][3] * inv);
    *(ushort4*)(op + i * 16 + quad * 4) = ov;
  }
}

extern "C" void kernel_launch(void* const* d_in, const int* in_sizes, int n_in,
                              void* d_out, int out_size, void* d_ws, size_t ws_size,
                              hipStream_t stream) {
  const float* x = (const float*)d_in[0];
  const float* cond = (const float*)d_in[1];
  const float* attn_bias = (const float*)d_in[2];
  const float* qkv_w = (const float*)d_in[3];
  const float* q_bias = (const float*)d_in[4];
  const float* v_bias = (const float*)d_in[5];
  const float* scale_mul = (const float*)d_in[6];
  const float* proj_w = (const float*)d_in[7];
  const float* proj_b = (const float*)d_in[8];
  const float* fc1_w = (const float*)d_in[9];
  const float* fc1_b = (const float*)d_in[10];
  const float* fc2_w = (const float*)d_in[11];
  const float* fc2_b = (const float*)d_in[12];
  const float* ada_w = (const float*)d_in[13];
  const float* ada_b = (const float*)d_in[14];
  float* out = (float*)d_out;
  char* ws = (char*)d_ws;

  float* ada_out = (float*)(ws + 0);                // 48 KB
  u16* wqkv = (u16*)(ws + 61440);                   // 6 MB
  u16* wproj = (u16*)(ws + 6352896);                // 2 MB
  u16* wfc1 = (u16*)(ws + 8450048);                 // 8 MB
  u16* wfc2 = (u16*)(ws + 16838656);                // 8 MB
  u16* sb = (u16*)(ws + 25227264);                  // 8 MB (h1 / o / h2)
  u16* big = (u16*)(ws + 33615872);                 // 32 MB (qkv+bias16 / proj partials / fc1out)
  float* g32 = (float*)(ws + 67170304);             // 16 MB (fc2 partial0)
  float* x2 = (float*)(ws + 83947520);              // 16 MB
  // bf16 bias*log2e in big's tail (8.4 MB); consumed by flash before proj
  // partials overwrite big (stream-ordered).
  u16* wbias = big + (size_t)4096 * 3072;
  float* projp0 = (float*)big;
  float* projp1 = (float*)(big + (size_t)8 * 1024 * 1024);
  float* fc2p1 = (float*)(ws + 61440);

  k_convert_all<<<16384, 256, 0, stream>>>(qkv_w, wqkv, proj_w, wproj,
                                           fc1_w, wfc1, fc2_w, wfc2,
                                           attn_bias, wbias);
  k_ada<<<3072, 256, 0, stream>>>(cond, ada_w, ada_b, ada_out);
  k_ln_mod<<<4096, 256, 0, stream>>>(x, ada_out, sb, 2048, 4096);
  k_gemm_qkv<<<dim3(32, 24), 256, 0, stream>>>(sb, wqkv, q_bias, v_bias,
                                               scale_mul, big);
  k_flash<<<dim3(32, 16), 512, 0, stream>>>(big, wbias, sb);
  k_gemm_bt<0, 0><<<dim3(32, 8, 2), 256, 0, stream>>>(sb, wproj, proj_b, projp0,
                                                      projp1, Mrows, 1024, 512);
  k_resid_ln<<<4096, 256, 0, stream>>>(x, projp0, projp1, ada_out, x2, sb);
  k_gemm_bt<1, 1><<<dim3(32, 32, 1), 256, 0, stream>>>(sb, wfc1, fc1_b, big,
                                                       nullptr, Mrows, 4096, 1024);
  k_gemm_bt<0, 0><<<dim3(32, 8, 2), 256, 0, stream>>>(big, wfc2, fc2_b, g32,
                                                      fc2p1, Mrows, 1024, 2048);
  k_final<<<4096, 256, 0, stream>>>(x2, g32, fc2p1, ada_out, out);
}